// Round 9
// baseline (247.114 us; speedup 1.0000x reference)
//
#include <hip/hip_runtime.h>
#include <math.h>

#define NB_B 16
#define NB_S 4096
#define NB_D 64
#define NB_H 8

// LDS strides (in halfs): rows 16B-aligned so fragments are single b128 ops.
#define KSTR 72
#define PSTR 136
#define VSTR 72

typedef _Float16 half_t;
typedef __attribute__((ext_vector_type(2))) _Float16 half2t;
typedef __attribute__((ext_vector_type(4))) _Float16 half4;
typedef __attribute__((ext_vector_type(8))) _Float16 half8;
typedef __attribute__((ext_vector_type(4))) float floatx4;

// ---------------- Kernel 0: precompute fp16 k-hat, v, f32 norm ----------------
__global__ __launch_bounds__(256) void prep_kernel(const float* __restrict__ qk,
                                                   const float* __restrict__ v,
                                                   half_t* __restrict__ khat,
                                                   half_t* __restrict__ vh,
                                                   float* __restrict__ norm) {
  int g = blockIdx.x * 256 + threadIdx.x;  // over B*S*16
  float4 qv = ((const float4*)qk)[g];
  float4 vv = ((const float4*)v)[g];
  float ss = qv.x * qv.x + qv.y * qv.y + qv.z * qv.z + qv.w * qv.w;
  for (int off = 1; off < 16; off <<= 1) ss += __shfl_xor(ss, off);
  float nr = fmaxf(sqrtf(ss), 1e-12f);
  float sc = 1.0f / nr;
  half4 hk = {(half_t)(qv.x * sc), (half_t)(qv.y * sc), (half_t)(qv.z * sc),
              (half_t)(qv.w * sc)};
  half4 hv = {(half_t)vv.x, (half_t)vv.y, (half_t)vv.z, (half_t)vv.w};
  ((half4*)khat)[g] = hk;
  ((half4*)vh)[g] = hv;
  if ((threadIdx.x & 15) == 0) norm[g >> 4] = nr;
}

// ---------------- Kernel 1a: approximate LSH hashing via MFMA ----------------
// rotated = Q @ rotT^T in fp16 MFMA (f32 acc). rms error vs strict f32
// ~3e-3; tokens whose top-2 gap < 0.0625 (>>20 sigma) are appended to a
// per-(b,h) fixup list; all others provably match np's argmax.
// grid: B*H*32 blocks (128 tokens each), 256 threads = 4 waves.
__global__ __launch_bounds__(256) void hash_mfma_kernel(const float* __restrict__ qk,
                                                        const float* __restrict__ rot,
                                                        int* __restrict__ bkt,
                                                        int* __restrict__ cnt,
                                                        int* __restrict__ list) {
  __shared__ __align__(16) half_t Qh[128 * 72];
  __shared__ __align__(16) half_t Rt[32 * 72];  // rot^T: [i][f]
  int tid = threadIdx.x;
  int blk = blockIdx.x;
  int tile = blk & 31, bh = blk >> 5;
  int h = bh & 7, b = bh >> 3;
  int t0 = tile << 7;

  for (int idx = tid; idx < 2048; idx += 256) {
    int f = idx >> 5, i = idx & 31;
    Rt[i * 72 + f] = (half_t)rot[(((size_t)b * 64 + f) * 8 + h) * 32 + i];
  }
  for (int idx = tid; idx < 1024; idx += 256) {
    int row = idx >> 3, fo = idx & 7;
    const float* src = qk + (((size_t)b << 12) + t0 + row) * 64 + fo * 8;
    float4 a = *(const float4*)src;
    float4 c = *(const float4*)(src + 4);
    half8 hv = {(half_t)a.x, (half_t)a.y, (half_t)a.z, (half_t)a.w,
                (half_t)c.x, (half_t)c.y, (half_t)c.z, (half_t)c.w};
    *(half8*)(Qh + row * 72 + fo * 8) = hv;
  }
  __syncthreads();

  int lane = tid & 63, w = tid >> 6;
  int m = lane & 15, quad = lane >> 4;
  half8 bfr[2][2];
#pragma unroll
  for (int nt = 0; nt < 2; nt++)
#pragma unroll
    for (int ki = 0; ki < 2; ki++)
      bfr[nt][ki] = *(const half8*)(Rt + (nt * 16 + m) * 72 + ki * 32 + quad * 8);

#pragma unroll
  for (int mt8 = 0; mt8 < 2; mt8++) {
    int mt = w + mt8 * 4;  // M-tile 0..7
    half8 afr[2];
#pragma unroll
    for (int ki = 0; ki < 2; ki++)
      afr[ki] = *(const half8*)(Qh + (mt * 16 + m) * 72 + ki * 32 + quad * 8);
    floatx4 acc0 = {0.f, 0.f, 0.f, 0.f}, acc1 = {0.f, 0.f, 0.f, 0.f};
#pragma unroll
    for (int ki = 0; ki < 2; ki++) {
      acc0 = __builtin_amdgcn_mfma_f32_16x16x32_f16(afr[ki], bfr[0][ki], acc0, 0, 0, 0);
      acc1 = __builtin_amdgcn_mfma_f32_16x16x32_f16(afr[ki], bfr[1][ki], acc1, 0, 0, 0);
    }
    // per-row top-2 with first-occurrence argmax over [rot, -rot] (64 cands)
#pragma unroll
    for (int r = 0; r < 4; r++) {
      float a0 = acc0[r], a1 = acc1[r];
      float v1 = a0, v2;
      int i1 = m;
      if (a1 > v1) { v2 = v1; v1 = a1; i1 = 16 + m; } else v2 = a1;
      float na0 = -a0;
      if (na0 > v1) { v2 = v1; v1 = na0; i1 = 32 + m; } else if (na0 > v2) v2 = na0;
      float na1 = -a1;
      if (na1 > v1) { v2 = v1; v1 = na1; i1 = 48 + m; } else if (na1 > v2) v2 = na1;
#pragma unroll
      for (int off = 1; off < 16; off <<= 1) {
        float ov1 = __shfl_xor(v1, off);
        int oi1 = __shfl_xor(i1, off);
        float ov2 = __shfl_xor(v2, off);
        bool take = (ov1 > v1) || (ov1 == v1 && oi1 < i1);
        float nv2 = take ? fmaxf(ov2, v1) : fmaxf(v2, ov1);
        v1 = take ? ov1 : v1;
        i1 = take ? oi1 : i1;
        v2 = nv2;
      }
      if (m == 0) {
        int token = t0 + mt * 16 + quad * 4 + r;
        bkt[((size_t)bh << 12) + token] = i1;
        if (v1 - v2 < 0.0625f) {
          int pos = atomicAdd(&cnt[bh], 1);
          list[(bh << 12) + (pos & 4095)] = token;
        }
      }
    }
  }
}

// ---------------- Kernel 1b: exact fixup for near-tie tokens ----------------
// Strict bit-faithful np.einsum-f32 mimic (sequential f, round(mul) then
// round(add), no fma). Standalone single-path kernel (R6 lesson: a second
// path in the same kernel spills to scratch). grid: B*H blocks.
__global__ __launch_bounds__(256) void hash_fixup_kernel(const float* __restrict__ qk,
                                                         const float* __restrict__ rot,
                                                         const int* __restrict__ cnt,
                                                         const int* __restrict__ list,
                                                         int* __restrict__ bkt) {
  __shared__ float rotS[64 * 32];  // [f][i]
  int tid = threadIdx.x;
  int bh = blockIdx.x;
  int h = bh & 7, b = bh >> 3;
  for (int i = tid; i < 2048; i += 256) {
    int f = i >> 5, ii = i & 31;
    rotS[i] = rot[(((size_t)b * 64 + f) * 8 + h) * 32 + ii];
  }
  __syncthreads();
  int n = cnt[bh];
  if (n > 4096) n = 4096;
  for (int j = tid; j < n; j += 256) {
    int t = list[(bh << 12) + j];
    const float4* qrow = (const float4*)(qk + (((size_t)b << 12) + t) * 64);
    float qreg[64];
#pragma unroll
    for (int jj = 0; jj < 16; jj++) *(float4*)(qreg + 4 * jj) = qrow[jj];
    float acc[32];
#pragma unroll
    for (int i = 0; i < 32; i++) acc[i] = 0.f;
#pragma unroll
    for (int f = 0; f < 64; f++) {
      float qf = qreg[f];
#pragma unroll
      for (int i4 = 0; i4 < 8; i4++) {
        float4 wv = *(const float4*)(rotS + f * 32 + i4 * 4);
        acc[i4 * 4 + 0] = __fadd_rn(acc[i4 * 4 + 0], __fmul_rn(qf, wv.x));
        acc[i4 * 4 + 1] = __fadd_rn(acc[i4 * 4 + 1], __fmul_rn(qf, wv.y));
        acc[i4 * 4 + 2] = __fadd_rn(acc[i4 * 4 + 2], __fmul_rn(qf, wv.z));
        acc[i4 * 4 + 3] = __fadd_rn(acc[i4 * 4 + 3], __fmul_rn(qf, wv.w));
      }
    }
    float b1 = acc[0];
    int i1 = 0;
#pragma unroll
    for (int i = 1; i < 32; i++)
      if (acc[i] > b1) { b1 = acc[i]; i1 = i; }
#pragma unroll
    for (int i = 0; i < 32; i++) {
      float x = -acc[i];
      if (x > b1) { b1 = x; i1 = 32 + i; }
    }
    bkt[((size_t)bh << 12) + t] = i1;
  }
}

// ---------------- Kernel 2: stable counting sort per (b,h) ----------------
__global__ __launch_bounds__(256) void sort_kernel(const int* __restrict__ bkt,
                                                   int* __restrict__ st) {
  __shared__ int lb[4096];
  __shared__ int hist[4096];  // [chunk(64)][bucket(64)]
  __shared__ int cumoff[64];
  int tid = threadIdx.x;
  int b = blockIdx.x >> 3, h = blockIdx.x & 7;
  const int* gb = bkt + (((size_t)(b * 8 + h)) << 12);
  for (int t = tid; t < 4096; t += 256) lb[t] = gb[t];
  for (int i = tid; i < 4096; i += 256) hist[i] = 0;
  __syncthreads();
  for (int t = tid; t < 4096; t += 256) atomicAdd(&hist[((t >> 6) << 6) | lb[t]], 1);
  __syncthreads();
  if (tid < 64) {
    int run = 0;
    for (int cc = 0; cc < 64; cc++) {
      int x = hist[(cc << 6) | tid];
      hist[(cc << 6) | tid] = run;
      run += x;
    }
    int s = run;
    for (int off = 1; off < 64; off <<= 1) {
      int u = __shfl_up(s, off);
      if (tid >= off) s += u;
    }
    cumoff[tid] = s - run;
  }
  __syncthreads();
  int lane = tid & 63;
  for (int p = 0; p < 16; p++) {
    int t = (p << 8) + tid;  // each wave covers one aligned 64-token chunk
    int vb = lb[t];
    unsigned long long m = 0xFFFFFFFFFFFFFFFFull;
#pragma unroll
    for (int bit = 0; bit < 6; bit++) {
      unsigned long long bl = __ballot((vb >> bit) & 1);
      m &= ((vb >> bit) & 1) ? bl : ~bl;
    }
    int rank = __popcll(m & ((1ull << lane) - 1ull));
    int cpos = cumoff[vb] + hist[((t >> 6) << 6) | vb] + rank;
    st[(((size_t)(b * 8 + h)) << 12) + cpos] = t;
  }
}

// ---------------- Kernel 3: fused chunk kernel ----------------
// QK^T (MFMA) -> softmax with analytic shift mm = |q|/8 (Cauchy-Schwarz)
// -> O^T = Vt*P (MFMA) -> direct half4 global stores.
__global__ __launch_bounds__(256) void chunk_kernel(const half_t* __restrict__ khat,
                                                    const half_t* __restrict__ vh,
                                                    const float* __restrict__ norm,
                                                    const int* __restrict__ st,
                                                    half_t* __restrict__ oh,
                                                    float* __restrict__ lse) {
  __shared__ __align__(16) half_t Ks[128 * KSTR];  // K; later P (64 rows, PSTR)
  __shared__ __align__(16) half_t Vt[64 * VSTR];   // V^T half: [dim][key]
  __shared__ int tk[128];
  __shared__ float normS[64];
  __shared__ float invS[64];
  int tid = threadIdx.x;
  int g = blockIdx.x & 511;
  int b = blockIdx.x >> 9;
  int h = g >> 6, c = g & 63;
  int gp = (g + 511) & 511;
  int hp = gp >> 6, cp = gp & 63;
  if (tid < 64) {
    tk[tid] = st[(((size_t)(b * 8 + h)) << 12) + (c << 6) + tid];
  } else if (tid < 128) {
    tk[tid] = st[(((size_t)(b * 8 + hp)) << 12) + (cp << 6) + (tid - 64)];
  }
  __syncthreads();
  if (tid < 64) normS[tid] = norm[(b << 12) + tk[tid]];
  for (int idx = tid; idx < 1024; idx += 256) {
    int row = idx >> 3, fo = idx & 7;
    half8 val = *(const half8*)(khat + (((size_t)(b << 12) + tk[row]) << 6) + fo * 8);
    *(half8*)(Ks + row * KSTR + fo * 8) = val;
  }
  {
    int kp = tid & 31, ch = tid >> 5;  // ch in 0..7
    half8 r0 = *(const half8*)(vh + (((size_t)(b << 12) + tk[2 * kp]) << 6) + ch * 8);
    half8 r1 = *(const half8*)(vh + (((size_t)(b << 12) + tk[2 * kp + 1]) << 6) + ch * 8);
#pragma unroll
    for (int j = 0; j < 8; j++) {
      half2t pr = {r0[j], r1[j]};
      *(half2t*)(Vt + (ch * 8 + j) * VSTR + 2 * kp) = pr;
    }
  }
  __syncthreads();

  int lane = tid & 63, w = tid >> 6;
  int m = lane & 15, quad = lane >> 4;
  half8 afr[2];
#pragma unroll
  for (int ki = 0; ki < 2; ki++)
    afr[ki] = *(const half8*)(Ks + (w * 16 + m) * KSTR + ki * 32 + quad * 8);
  int ti[4];
  float scr[4];
#pragma unroll
  for (int r = 0; r < 4; r++) {
    int rr = w * 16 + quad * 4 + r;
    ti[r] = tk[rr];
    scr[r] = 0.125f * normS[rr];
  }

  float p[8][4];
#pragma unroll
  for (int nt = 0; nt < 8; nt++) {
    floatx4 acc = {0.f, 0.f, 0.f, 0.f};
#pragma unroll
    for (int ki = 0; ki < 2; ki++) {
      half8 bfr = *(const half8*)(Ks + (nt * 16 + m) * KSTR + ki * 32 + quad * 8);
      acc = __builtin_amdgcn_mfma_f32_16x16x32_f16(afr[ki], bfr, acc, 0, 0, 0);
    }
    int tj = tk[nt * 16 + m];
#pragma unroll
    for (int r = 0; r < 4; r++)
      p[nt][r] = (ti[r] == tj) ? 0.f : __expf(fmaf(acc[r], scr[r], -scr[r]));
  }

  float lr[4];
#pragma unroll
  for (int r = 0; r < 4; r++) {
    float ll = 0.f;
#pragma unroll
    for (int nt = 0; nt < 8; nt++) ll += p[nt][r];
    for (int off = 1; off < 16; off <<= 1) ll += __shfl_xor(ll, off);
    lr[r] = ll;
    if (m == 0) {
      lse[(((size_t)(b * 8 + h)) << 12) + ti[r]] = scr[r] + __logf(ll);
      invS[w * 16 + quad * 4 + r] = 1.0f / ll;
    }
  }
  __syncthreads();  // all waves done reading Ks as K

  half_t* Ps = Ks;
#pragma unroll
  for (int nt = 0; nt < 8; nt++) {
#pragma unroll
    for (int r = 0; r < 4; r++) {
      Ps[(w * 16 + quad * 4 + r) * PSTR + nt * 16 + m] = (half_t)p[nt][r];
    }
  }
  __syncthreads();

  half8 pfr[4];
#pragma unroll
  for (int kk = 0; kk < 4; kk++)
    pfr[kk] = *(const half8*)(Ps + (w * 16 + m) * PSTR + kk * 32 + quad * 8);

  floatx4 accO[4];
#pragma unroll
  for (int dt = 0; dt < 4; dt++) accO[dt] = (floatx4){0.f, 0.f, 0.f, 0.f};

#pragma unroll
  for (int dt = 0; dt < 4; dt++) {
#pragma unroll
    for (int kk = 0; kk < 2; kk++) {
      half8 vfr = *(const half8*)(Vt + (dt * 16 + m) * VSTR + kk * 32 + quad * 8);
      accO[dt] = __builtin_amdgcn_mfma_f32_16x16x32_f16(vfr, pfr[kk], accO[dt], 0, 0, 0);
    }
  }
  __syncthreads();  // V half 0 reads done

  {
    int kp = tid & 31, ch = tid >> 5;
    half8 r0 = *(const half8*)(vh + (((size_t)(b << 12) + tk[64 + 2 * kp]) << 6) + ch * 8);
    half8 r1 = *(const half8*)(vh + (((size_t)(b << 12) + tk[65 + 2 * kp]) << 6) + ch * 8);
#pragma unroll
    for (int j = 0; j < 8; j++) {
      half2t pr = {r0[j], r1[j]};
      *(half2t*)(Vt + (ch * 8 + j) * VSTR + 2 * kp) = pr;
    }
  }
  __syncthreads();

#pragma unroll
  for (int dt = 0; dt < 4; dt++) {
#pragma unroll
    for (int kk = 2; kk < 4; kk++) {
      half8 vfr = *(const half8*)(Vt + (dt * 16 + m) * VSTR + (kk - 2) * 32 + quad * 8);
      accO[dt] = __builtin_amdgcn_mfma_f32_16x16x32_f16(vfr, pfr[kk], accO[dt], 0, 0, 0);
    }
  }

  {
    int tt = tk[w * 16 + m];
    float inv = invS[w * 16 + m];
    half_t* dst = oh + ((((size_t)(b * 8 + h)) << 12) + tt) * 64 + quad * 4;
#pragma unroll
    for (int dt = 0; dt < 4; dt++) {
      half4 ov = {(half_t)(accO[dt][0] * inv), (half_t)(accO[dt][1] * inv),
                  (half_t)(accO[dt][2] * inv), (half_t)(accO[dt][3] * inv)};
      *(half4*)(dst + dt * 16) = ov;
    }
  }
}

// ---------------- Kernel 4: combine rounds ----------------
__global__ __launch_bounds__(256) void combine_kernel(const half_t* __restrict__ oh,
                                                      const float* __restrict__ lse,
                                                      float* __restrict__ out) {
  int idx = blockIdx.x * 256 + threadIdx.x;  // over B*S*8
  int do8 = idx & 7;
  int ts = idx >> 3;  // b*4096 + t
  int b = ts >> 12, t = ts & 4095;
  size_t base = ((size_t)b << 15) + t;  // (b*8)<<12 + t
  float L[8];
  float m = -3.4e38f;
#pragma unroll
  for (int h = 0; h < 8; h++) {
    L[h] = lse[base + ((size_t)h << 12)];
    m = fmaxf(m, L[h]);
  }
  float s = 0.f;
#pragma unroll
  for (int h = 0; h < 8; h++) s += __expf(L[h] - m);
  float lt = m + __logf(s);
  float acc[8];
#pragma unroll
  for (int j = 0; j < 8; j++) acc[j] = 0.f;
#pragma unroll
  for (int h = 0; h < 8; h++) {
    float wgt = __expf(L[h] - lt);
    half8 o = *(const half8*)(oh + ((base + ((size_t)h << 12)) << 6) + do8 * 8);
#pragma unroll
    for (int j = 0; j < 8; j++) acc[j] += wgt * (float)o[j];
  }
  float* dst = out + ((((size_t)b << 12) + t) << 6) + do8 * 8;
  *(float4*)dst = (float4){acc[0], acc[1], acc[2], acc[3]};
  *(float4*)(dst + 4) = (float4){acc[4], acc[5], acc[6], acc[7]};
}

extern "C" void kernel_launch(void* const* d_in, const int* in_sizes, int n_in,
                              void* d_out, int out_size, void* d_ws, size_t ws_size,
                              hipStream_t stream) {
  const float* qk = (const float*)d_in[0];
  const float* v = (const float*)d_in[1];
  const float* rot = (const float*)d_in[2];
  float* out = (float*)d_out;

  int* bkt = (int*)d_ws;                            // 2MB
  int* stp = bkt + NB_B * NB_H * NB_S;              // 2MB
  float* lse = (float*)(stp + NB_B * NB_H * NB_S);  // 2MB
  float* norm = lse + NB_B * NB_H * NB_S;           // 256KB
  half_t* khat = (half_t*)(norm + NB_B * NB_S);     // 8MB
  half_t* vh = khat + (size_t)NB_B * NB_S * NB_D;   // 8MB
  half_t* oh = vh + (size_t)NB_B * NB_S * NB_D;     // 67MB
  int* cnt = (int*)(oh + (size_t)NB_B * NB_H * NB_S * NB_D);  // 128 ints
  int* list = cnt + 128;                            // 2MB

  hipMemsetAsync(cnt, 0, 128 * sizeof(int), stream);
  prep_kernel<<<NB_B * NB_S * 16 / 256, 256, 0, stream>>>(qk, v, khat, vh, norm);
  hash_mfma_kernel<<<NB_B * NB_H * 32, 256, 0, stream>>>(qk, rot, bkt, cnt, list);
  hash_fixup_kernel<<<NB_B * NB_H, 256, 0, stream>>>(qk, rot, cnt, list, bkt);
  sort_kernel<<<NB_B * NB_H, 256, 0, stream>>>(bkt, stp);
  chunk_kernel<<<NB_B * 512, 256, 0, stream>>>(khat, vh, norm, stp, oh, lse);
  combine_kernel<<<NB_B * NB_S * 8 / 256, 256, 0, stream>>>(oh, lse, out);
}

// Round 10
// 214.620 us; speedup vs baseline: 1.1514x; 1.1514x over previous
//
#include <hip/hip_runtime.h>
#include <math.h>

#define NB_B 16
#define NB_S 4096
#define NB_D 64
#define NB_H 8

// LDS strides (in halfs): rows 16B-aligned so fragments are single b128 ops.
#define KSTR 72
#define PSTR 136
#define VSTR 72

typedef _Float16 half_t;
typedef __attribute__((ext_vector_type(2))) _Float16 half2t;
typedef __attribute__((ext_vector_type(4))) _Float16 half4;
typedef __attribute__((ext_vector_type(8))) _Float16 half8;
typedef __attribute__((ext_vector_type(4))) float floatx4;
typedef __attribute__((ext_vector_type(2))) float f32x2;

// ---------------- Kernel 0: precompute fp16 k-hat, v, f32 norm ----------------
__global__ __launch_bounds__(256) void prep_kernel(const float* __restrict__ qk,
                                                   const float* __restrict__ v,
                                                   half_t* __restrict__ khat,
                                                   half_t* __restrict__ vh,
                                                   float* __restrict__ norm) {
  int g = blockIdx.x * 256 + threadIdx.x;  // over B*S*16
  float4 qv = ((const float4*)qk)[g];
  float4 vv = ((const float4*)v)[g];
  float ss = qv.x * qv.x + qv.y * qv.y + qv.z * qv.z + qv.w * qv.w;
  for (int off = 1; off < 16; off <<= 1) ss += __shfl_xor(ss, off);
  float nr = fmaxf(sqrtf(ss), 1e-12f);
  float sc = 1.0f / nr;
  half4 hk = {(half_t)(qv.x * sc), (half_t)(qv.y * sc), (half_t)(qv.z * sc),
              (half_t)(qv.w * sc)};
  half4 hv = {(half_t)vv.x, (half_t)vv.y, (half_t)vv.z, (half_t)vv.w};
  ((half4*)khat)[g] = hk;
  ((half4*)vh)[g] = hv;
  if ((threadIdx.x & 15) == 0) norm[g >> 4] = nr;
}

// ---------------- Kernel 1: LSH hashing (buckets) ----------------
// Bit-faithful mimic of naive np.einsum float32. Strict mul-then-add per
// f-step (NO fma — contract(off)), f ascending. float2 ext-vector ops so
// clang can emit v_pk_mul_f32/v_pk_add_f32 (IEEE per half-lane => bit
// identical). SINGLE path, single kernel — R6's dual-path variant spilled
// to scratch (VGPR 256, 3.1 ms); R9's MFMA+fixup split regressed (+32 µs).
// This version is frozen.
__global__ __launch_bounds__(256) void hash_kernel(const float* __restrict__ qk,
                                                   const float* __restrict__ rot,
                                                   int* __restrict__ bkt) {
  __shared__ float rotS[64 * 32];  // [f][i]
  int tid = threadIdx.x;
  int blk = blockIdx.x;
  int tile = blk & 15, bh = blk >> 4;
  int h = bh & 7, b = bh >> 3;
  int t = (tile << 8) + tid;

  for (int i = tid; i < 2048; i += 256) {
    int f = i >> 5, ii = i & 31;
    rotS[i] = rot[(((size_t)b * 64 + f) * 8 + h) * 32 + ii];
  }
  __syncthreads();

  const float4* qrow = (const float4*)(qk + (((size_t)b << 12) + t) * 64);
  float qreg[64];
#pragma unroll
  for (int j = 0; j < 16; j++) *(float4*)(qreg + 4 * j) = qrow[j];

  f32x2 acc2[16];
#pragma unroll
  for (int i = 0; i < 16; i++) acc2[i] = (f32x2){0.f, 0.f};

  {
#pragma clang fp contract(off)
#pragma unroll
    for (int f = 0; f < 64; f++) {
      float qf = qreg[f];
      f32x2 q2 = {qf, qf};
      const f32x2* wrow = (const f32x2*)(rotS + f * 32);
#pragma unroll
      for (int i2 = 0; i2 < 16; i2++) {
        f32x2 prod = q2 * wrow[i2];   // rounded mul
        acc2[i2] = acc2[i2] + prod;   // rounded add
      }
    }
  }

  // first-occurrence argmax over concat([acc, -acc])
  float b1 = acc2[0][0];
  int i1 = 0;
#pragma unroll
  for (int i = 1; i < 32; i++) {
    float x = acc2[i >> 1][i & 1];
    if (x > b1) { b1 = x; i1 = i; }
  }
#pragma unroll
  for (int i = 0; i < 32; i++) {
    float x = -acc2[i >> 1][i & 1];
    if (x > b1) { b1 = x; i1 = 32 + i; }
  }
  bkt[(((size_t)(b * 8 + h)) << 12) + t] = i1;
}

// ---------------- Kernel 2: stable counting sort per (b,h) ----------------
// Scan parallelized across all 256 threads: 4 parts x 64 buckets; each
// part sums 16 chunks, 4-way cross-part prefix, then rewrites 16 entries.
// Critical path ~4x shorter than the old 64-thread x 64-iter serial scan.
__global__ __launch_bounds__(256) void sort_kernel(const int* __restrict__ bkt,
                                                   int* __restrict__ st) {
  __shared__ int lb[4096];
  __shared__ int hist[4096];  // [chunk(64)][bucket(64)]
  __shared__ int psum[4][64];
  __shared__ int totS[64];
  __shared__ int cumoff[64];
  int tid = threadIdx.x;
  int b = blockIdx.x >> 3, h = blockIdx.x & 7;
  const int* gb = bkt + (((size_t)(b * 8 + h)) << 12);
  for (int t = tid; t < 4096; t += 256) lb[t] = gb[t];
  for (int i = tid; i < 4096; i += 256) hist[i] = 0;
  __syncthreads();
  for (int t = tid; t < 4096; t += 256) atomicAdd(&hist[((t >> 6) << 6) | lb[t]], 1);
  __syncthreads();
  int vb = tid & 63, part = tid >> 6;
  {
    int s = 0;
#pragma unroll
    for (int cc = part * 16; cc < part * 16 + 16; cc++) s += hist[(cc << 6) | vb];
    psum[part][vb] = s;
  }
  __syncthreads();
  int off = 0;
#pragma unroll
  for (int pp = 0; pp < 4; pp++) {
    int x = psum[pp][vb];
    if (pp < part) off += x;
  }
  if (part == 3) totS[vb] = off + psum[3][vb];
  {
    int run = off;
#pragma unroll
    for (int cc = part * 16; cc < part * 16 + 16; cc++) {
      int x = hist[(cc << 6) | vb];
      hist[(cc << 6) | vb] = run;
      run += x;
    }
  }
  __syncthreads();
  if (tid < 64) {
    int tv = totS[tid];
    int s = tv;
    for (int o2 = 1; o2 < 64; o2 <<= 1) {
      int u = __shfl_up(s, o2);
      if (tid >= o2) s += u;
    }
    cumoff[tid] = s - tv;
  }
  __syncthreads();
  int lane = tid & 63;
  for (int p = 0; p < 16; p++) {
    int t = (p << 8) + tid;  // each wave covers one aligned 64-token chunk
    int vbt = lb[t];
    unsigned long long m = 0xFFFFFFFFFFFFFFFFull;
#pragma unroll
    for (int bit = 0; bit < 6; bit++) {
      unsigned long long bl = __ballot((vbt >> bit) & 1);
      m &= ((vbt >> bit) & 1) ? bl : ~bl;
    }
    int rank = __popcll(m & ((1ull << lane) - 1ull));
    int cpos = cumoff[vbt] + hist[((t >> 6) << 6) | vbt] + rank;
    st[(((size_t)(b * 8 + h)) << 12) + cpos] = t;
  }
}

// ---------------- Kernel 3: fused chunk kernel ----------------
// QK^T (MFMA) -> softmax with analytic shift mm = |q|/8 (Cauchy-Schwarz)
// -> O^T = Vt*P (MFMA) -> direct half4 global stores. FROZEN: three
// micro-tuning rounds (b128 strides, max-free softmax, O-bounce removal)
// were all neutral — it is latency/barrier-structured, not pipe-bound.
__global__ __launch_bounds__(256) void chunk_kernel(const half_t* __restrict__ khat,
                                                    const half_t* __restrict__ vh,
                                                    const float* __restrict__ norm,
                                                    const int* __restrict__ st,
                                                    half_t* __restrict__ oh,
                                                    float* __restrict__ lse) {
  __shared__ __align__(16) half_t Ks[128 * KSTR];  // K; later P (64 rows, PSTR)
  __shared__ __align__(16) half_t Vt[64 * VSTR];   // V^T half: [dim][key]
  __shared__ int tk[128];
  __shared__ float normS[64];
  __shared__ float invS[64];
  int tid = threadIdx.x;
  int g = blockIdx.x & 511;
  int b = blockIdx.x >> 9;
  int h = g >> 6, c = g & 63;
  int gp = (g + 511) & 511;
  int hp = gp >> 6, cp = gp & 63;
  if (tid < 64) {
    tk[tid] = st[(((size_t)(b * 8 + h)) << 12) + (c << 6) + tid];
  } else if (tid < 128) {
    tk[tid] = st[(((size_t)(b * 8 + hp)) << 12) + (cp << 6) + (tid - 64)];
  }
  __syncthreads();
  if (tid < 64) normS[tid] = norm[(b << 12) + tk[tid]];
  for (int idx = tid; idx < 1024; idx += 256) {
    int row = idx >> 3, fo = idx & 7;
    half8 val = *(const half8*)(khat + (((size_t)(b << 12) + tk[row]) << 6) + fo * 8);
    *(half8*)(Ks + row * KSTR + fo * 8) = val;
  }
  {
    int kp = tid & 31, ch = tid >> 5;  // ch in 0..7
    half8 r0 = *(const half8*)(vh + (((size_t)(b << 12) + tk[2 * kp]) << 6) + ch * 8);
    half8 r1 = *(const half8*)(vh + (((size_t)(b << 12) + tk[2 * kp + 1]) << 6) + ch * 8);
#pragma unroll
    for (int j = 0; j < 8; j++) {
      half2t pr = {r0[j], r1[j]};
      *(half2t*)(Vt + (ch * 8 + j) * VSTR + 2 * kp) = pr;
    }
  }
  __syncthreads();

  int lane = tid & 63, w = tid >> 6;
  int m = lane & 15, quad = lane >> 4;
  half8 afr[2];
#pragma unroll
  for (int ki = 0; ki < 2; ki++)
    afr[ki] = *(const half8*)(Ks + (w * 16 + m) * KSTR + ki * 32 + quad * 8);
  int ti[4];
  float scr[4];
#pragma unroll
  for (int r = 0; r < 4; r++) {
    int rr = w * 16 + quad * 4 + r;
    ti[r] = tk[rr];
    scr[r] = 0.125f * normS[rr];
  }

  float p[8][4];
#pragma unroll
  for (int nt = 0; nt < 8; nt++) {
    floatx4 acc = {0.f, 0.f, 0.f, 0.f};
#pragma unroll
    for (int ki = 0; ki < 2; ki++) {
      half8 bfr = *(const half8*)(Ks + (nt * 16 + m) * KSTR + ki * 32 + quad * 8);
      acc = __builtin_amdgcn_mfma_f32_16x16x32_f16(afr[ki], bfr, acc, 0, 0, 0);
    }
    int tj = tk[nt * 16 + m];
#pragma unroll
    for (int r = 0; r < 4; r++)
      p[nt][r] = (ti[r] == tj) ? 0.f : __expf(fmaf(acc[r], scr[r], -scr[r]));
  }

  float lr[4];
#pragma unroll
  for (int r = 0; r < 4; r++) {
    float ll = 0.f;
#pragma unroll
    for (int nt = 0; nt < 8; nt++) ll += p[nt][r];
    for (int off = 1; off < 16; off <<= 1) ll += __shfl_xor(ll, off);
    lr[r] = ll;
    if (m == 0) {
      lse[(((size_t)(b * 8 + h)) << 12) + ti[r]] = scr[r] + __logf(ll);
      invS[w * 16 + quad * 4 + r] = 1.0f / ll;
    }
  }
  __syncthreads();  // all waves done reading Ks as K

  half_t* Ps = Ks;
#pragma unroll
  for (int nt = 0; nt < 8; nt++) {
#pragma unroll
    for (int r = 0; r < 4; r++) {
      Ps[(w * 16 + quad * 4 + r) * PSTR + nt * 16 + m] = (half_t)p[nt][r];
    }
  }
  __syncthreads();

  half8 pfr[4];
#pragma unroll
  for (int kk = 0; kk < 4; kk++)
    pfr[kk] = *(const half8*)(Ps + (w * 16 + m) * PSTR + kk * 32 + quad * 8);

  floatx4 accO[4];
#pragma unroll
  for (int dt = 0; dt < 4; dt++) accO[dt] = (floatx4){0.f, 0.f, 0.f, 0.f};

#pragma unroll
  for (int dt = 0; dt < 4; dt++) {
#pragma unroll
    for (int kk = 0; kk < 2; kk++) {
      half8 vfr = *(const half8*)(Vt + (dt * 16 + m) * VSTR + kk * 32 + quad * 8);
      accO[dt] = __builtin_amdgcn_mfma_f32_16x16x32_f16(vfr, pfr[kk], accO[dt], 0, 0, 0);
    }
  }
  __syncthreads();  // V half 0 reads done

  {
    int kp = tid & 31, ch = tid >> 5;
    half8 r0 = *(const half8*)(vh + (((size_t)(b << 12) + tk[64 + 2 * kp]) << 6) + ch * 8);
    half8 r1 = *(const half8*)(vh + (((size_t)(b << 12) + tk[65 + 2 * kp]) << 6) + ch * 8);
#pragma unroll
    for (int j = 0; j < 8; j++) {
      half2t pr = {r0[j], r1[j]};
      *(half2t*)(Vt + (ch * 8 + j) * VSTR + 2 * kp) = pr;
    }
  }
  __syncthreads();

#pragma unroll
  for (int dt = 0; dt < 4; dt++) {
#pragma unroll
    for (int kk = 2; kk < 4; kk++) {
      half8 vfr = *(const half8*)(Vt + (dt * 16 + m) * VSTR + (kk - 2) * 32 + quad * 8);
      accO[dt] = __builtin_amdgcn_mfma_f32_16x16x32_f16(vfr, pfr[kk], accO[dt], 0, 0, 0);
    }
  }

  {
    int tt = tk[w * 16 + m];
    float inv = invS[w * 16 + m];
    half_t* dst = oh + ((((size_t)(b * 8 + h)) << 12) + tt) * 64 + quad * 4;
#pragma unroll
    for (int dt = 0; dt < 4; dt++) {
      half4 ov = {(half_t)(accO[dt][0] * inv), (half_t)(accO[dt][1] * inv),
                  (half_t)(accO[dt][2] * inv), (half_t)(accO[dt][3] * inv)};
      *(half4*)(dst + dt * 16) = ov;
    }
  }
}

// ---------------- Kernel 4: combine rounds ----------------
__global__ __launch_bounds__(256) void combine_kernel(const half_t* __restrict__ oh,
                                                      const float* __restrict__ lse,
                                                      float* __restrict__ out) {
  int idx = blockIdx.x * 256 + threadIdx.x;  // over B*S*8
  int do8 = idx & 7;
  int ts = idx >> 3;  // b*4096 + t
  int b = ts >> 12, t = ts & 4095;
  size_t base = ((size_t)b << 15) + t;  // (b*8)<<12 + t
  float L[8];
  float m = -3.4e38f;
#pragma unroll
  for (int h = 0; h < 8; h++) {
    L[h] = lse[base + ((size_t)h << 12)];
    m = fmaxf(m, L[h]);
  }
  float s = 0.f;
#pragma unroll
  for (int h = 0; h < 8; h++) s += __expf(L[h] - m);
  float lt = m + __logf(s);
  float acc[8];
#pragma unroll
  for (int j = 0; j < 8; j++) acc[j] = 0.f;
#pragma unroll
  for (int h = 0; h < 8; h++) {
    float wgt = __expf(L[h] - lt);
    half8 o = *(const half8*)(oh + ((base + ((size_t)h << 12)) << 6) + do8 * 8);
#pragma unroll
    for (int j = 0; j < 8; j++) acc[j] += wgt * (float)o[j];
  }
  float* dst = out + ((((size_t)b << 12) + t) << 6) + do8 * 8;
  *(float4*)dst = (float4){acc[0], acc[1], acc[2], acc[3]};
  *(float4*)(dst + 4) = (float4){acc[4], acc[5], acc[6], acc[7]};
}

extern "C" void kernel_launch(void* const* d_in, const int* in_sizes, int n_in,
                              void* d_out, int out_size, void* d_ws, size_t ws_size,
                              hipStream_t stream) {
  const float* qk = (const float*)d_in[0];
  const float* v = (const float*)d_in[1];
  const float* rot = (const float*)d_in[2];
  float* out = (float*)d_out;

  int* bkt = (int*)d_ws;                            // 2MB
  int* stp = bkt + NB_B * NB_H * NB_S;              // 2MB
  float* lse = (float*)(stp + NB_B * NB_H * NB_S);  // 2MB
  float* norm = lse + NB_B * NB_H * NB_S;           // 256KB
  half_t* khat = (half_t*)(norm + NB_B * NB_S);     // 8MB
  half_t* vh = khat + (size_t)NB_B * NB_S * NB_D;   // 8MB
  half_t* oh = vh + (size_t)NB_B * NB_S * NB_D;     // B*H*S*D fp16 = 67MB

  prep_kernel<<<NB_B * NB_S * 16 / 256, 256, 0, stream>>>(qk, v, khat, vh, norm);
  hash_kernel<<<NB_B * NB_H * 16, 256, 0, stream>>>(qk, rot, bkt);
  sort_kernel<<<NB_B * NB_H, 256, 0, stream>>>(bkt, stp);
  chunk_kernel<<<NB_B * 512, 256, 0, stream>>>(khat, vh, norm, stp, oh, lse);
  combine_kernel<<<NB_B * NB_S * 8 / 256, 256, 0, stream>>>(oh, lse, out);
}